// Round 4
// baseline (130.971 us; speedup 1.0000x reference)
//
#include <hip/hip_runtime.h>
#include <hip/hip_fp16.h>

// Problem constants (from reference)
constexpr int BATCH    = 4096;
constexpr int IN_DIM   = 1024;
constexpr int HIDDEN   = 8192;
constexpr int N_LAYERS = 6;
constexpr int OUT_DIM  = 8;
constexpr float INV_TAU = 0.1f;

// Tiling
constexpr int TB   = 4;             // batch rows per workgroup
constexpr int NTH  = 1024;          // threads per block (16 waves)
constexpr int NPT  = HIDDEN / NTH;  // neurons per thread = 8 (consecutive)
constexpr int NWAVES = NTH / 64;    // 16

__device__ __forceinline__ __half2 u2h(unsigned int u) {
    union { unsigned int u; __half2 h; } v; v.u = u; return v.h;
}
__device__ __forceinline__ unsigned int h2u(__half2 h) {
    union { unsigned int u; __half2 h; } v; v.h = h; return v.u;
}

// pack 4 fp32 -> 4 fp16 in a uint2
__device__ __forceinline__ uint2 pack4(float4 v) {
    __half2 lo = __float22half2_rn(make_float2(v.x, v.y));
    __half2 hi = __float22half2_rn(make_float2(v.z, v.w));
    uint2 r; r.x = h2u(lo); r.y = h2u(hi); return r;
}
__device__ __forceinline__ float4 unpack4(uint2 p) {
    float2 a = __half22float2(u2h(p.x));
    float2 b = __half22float2(u2h(p.y));
    return make_float4(a.x, a.y, b.x, b.y);
}

// ---------------------------------------------------------------------------
// Kernel 1: packed per-neuron records:
//   coefp[l*H+j] = 4 fp16 gate coefs (c0,c1 | c2,c3)
//   idxp [l*H+j] = ia | (ib << 16)
// ---------------------------------------------------------------------------
__global__ void prep_kernel(const float* __restrict__ logic_w,
                            const int* __restrict__ idx0_a,
                            const int* __restrict__ idx0_b,
                            const int* __restrict__ idx_a,
                            const int* __restrict__ idx_b,
                            uint2* __restrict__ coefp,
                            unsigned int* __restrict__ idxp, int n)
{
    int id = blockIdx.x * blockDim.x + threadIdx.x;
    if (id >= n) return;
    const int l = id / HIDDEN;
    const int j = id - l * HIDDEN;

    int ia, ib;
    if (l == 0) { ia = idx0_a[j]; ib = idx0_b[j]; }
    else        { ia = idx_a[(size_t)(l - 1) * HIDDEN + j];
                  ib = idx_b[(size_t)(l - 1) * HIDDEN + j]; }
    idxp[id] = (unsigned int)ia | ((unsigned int)ib << 16);

    const float4* w4 = (const float4*)(logic_w + (size_t)id * 16);
    float4 wa = w4[0], wb = w4[1], wc = w4[2], wd = w4[3];
    float wv[16] = {wa.x, wa.y, wa.z, wa.w, wb.x, wb.y, wb.z, wb.w,
                    wc.x, wc.y, wc.z, wc.w, wd.x, wd.y, wd.z, wd.w};
    float m = wv[0];
#pragma unroll
    for (int i = 1; i < 16; ++i) m = fmaxf(m, wv[i]);
    float e[16];
    float s = 0.f;
#pragma unroll
    for (int i = 0; i < 16; ++i) { e[i] = expf(wv[i] - m); s += e[i]; }
    float inv = 1.f / s;
    const float G0[16] = {0,0,0,0,0,0,0,0, 1,1,1,1,1,1,1,1};
    const float G1[16] = {0,0,1,1,0,0,1,1, -1,-1,0,0,-1,-1,0,0};
    const float G2[16] = {0,0,0,0,1,1,1,1, -1,-1,-1,-1,0,0,0,0};
    const float G3[16] = {0,1,-1,0,-1,0,-2,-1, 1,2,0,1,0,1,-1,0};
    float c0 = 0.f, c1 = 0.f, c2 = 0.f, c3 = 0.f;
#pragma unroll
    for (int i = 0; i < 16; ++i) {
        float p = e[i] * inv;
        c0 = fmaf(p, G0[i], c0);
        c1 = fmaf(p, G1[i], c1);
        c2 = fmaf(p, G2[i], c2);
        c3 = fmaf(p, G3[i], c3);
    }
    coefp[id] = pack4(make_float4(c0, c1, c2, c3));
}

// gate in packed fp16: r = (c0 + c1*a) + b*(c2 + c3*a), both half2 halves.
// c.x = (c0|c1), c.y = (c2|c3); splats fold into v_pk op_sel.
__device__ __forceinline__ uint2 gateh(uint2 a, uint2 b, uint2 c) {
    __half2 cp01 = u2h(c.x), cp23 = u2h(c.y);
    __half2 c0 = __low2half2(cp01), c1 = __high2half2(cp01);
    __half2 c2 = __low2half2(cp23), c3 = __high2half2(cp23);
    __half2 alo = u2h(a.x), ahi = u2h(a.y);
    __half2 blo = u2h(b.x), bhi = u2h(b.y);
    __half2 rlo = __hfma2(blo, __hfma2(c3, alo, c2), __hfma2(c1, alo, c0));
    __half2 rhi = __hfma2(bhi, __hfma2(c3, ahi, c2), __hfma2(c1, ahi, c0));
    uint2 r; r.x = h2u(rlo); r.y = h2u(rhi); return r;
}

// ---------------------------------------------------------------------------
// Kernel 2: fused network. TB=4 rows/block, h = fp16x4 (uint2)[HIDDEN] = 64 KB
// -> 2 blocks/CU. Thread owns 8 CONSECUTIVE neurons (b128 idx/coef loads,
// b128 contiguous LDS writes). Gate math entirely in v_pk_fma_f16.
// ---------------------------------------------------------------------------
__global__ __launch_bounds__(NTH) void net_kernel(
    const float*  __restrict__ x,
    const uint2*  __restrict__ coefp,
    const unsigned int* __restrict__ idxp,
    const float*  __restrict__ scaler_w, const float* __restrict__ scaler_b,
    float* __restrict__ out)
{
    __shared__ uint2 h[HIDDEN];             // 64 KB
    __shared__ uint2 hx[IN_DIM];            // 8 KB
    __shared__ float4 warr[NWAVES];         // 256 B
    __shared__ float  vals[TB][OUT_DIM];    // 128 B

    const int tid = threadIdx.x;
    const int b0  = blockIdx.x * TB;

    // Load + binarize input tile (NTH == IN_DIM)
    {
        float4 xv;
        xv.x = (x[(size_t)(b0 + 0) * IN_DIM + tid] > 0.5f) ? 1.f : 0.f;
        xv.y = (x[(size_t)(b0 + 1) * IN_DIM + tid] > 0.5f) ? 1.f : 0.f;
        xv.z = (x[(size_t)(b0 + 2) * IN_DIM + tid] > 0.5f) ? 1.f : 0.f;
        xv.w = (x[(size_t)(b0 + 3) * IN_DIM + tid] > 0.5f) ? 1.f : 0.f;
        hx[tid] = pack4(xv);
    }
    __syncthreads();

    uint2 acc[NPT];                          // fp16-packed results
    const int jb = tid * NPT;                // 8 consecutive neurons

    // Layer 0: gather from hx
    {
        const uint4* ip4 = (const uint4*)(idxp + jb);        // 2x uint4
        const uint4* cp4 = (const uint4*)(coefp + jb);       // 4x uint4
        uint4 ix[2] = {ip4[0], ip4[1]};
        uint4 cf[4] = {cp4[0], cp4[1], cp4[2], cp4[3]};
        const unsigned int* prs = (const unsigned int*)ix;
        const uint2*        cs  = (const uint2*)cf;
#pragma unroll
        for (int k = 0; k < NPT; ++k) {
            unsigned int pr = prs[k];
            acc[k] = gateh(hx[pr & 0xffffu], hx[pr >> 16], cs[k]);
        }
    }
    {
        uint4* hw = (uint4*)(h + jb);
#pragma unroll
        for (int k = 0; k < NPT / 2; ++k)
            hw[k] = make_uint4(acc[2*k].x, acc[2*k].y, acc[2*k+1].x, acc[2*k+1].y);
    }
    __syncthreads();

    // Layers 1..5: in-place on h (reads land in regs before writes)
    for (int l = 1; l < N_LAYERS; ++l) {
        const uint4* ip4 = (const uint4*)(idxp  + (size_t)l * HIDDEN + jb);
        const uint4* cp4 = (const uint4*)(coefp + (size_t)l * HIDDEN + jb);
        uint4 ix[2] = {ip4[0], ip4[1]};
        uint4 cf[4] = {cp4[0], cp4[1], cp4[2], cp4[3]};
        const unsigned int* prs = (const unsigned int*)ix;
        const uint2*        cs  = (const uint2*)cf;
#pragma unroll
        for (int k = 0; k < NPT; ++k) {
            unsigned int pr = prs[k];
            acc[k] = gateh(h[pr & 0xffffu], h[pr >> 16], cs[k]);
        }
        __syncthreads();                    // all reads of h done
        uint4* hw = (uint4*)(h + jb);
#pragma unroll
        for (int k = 0; k < NPT / 2; ++k)
            hw[k] = make_uint4(acc[2*k].x, acc[2*k].y, acc[2*k+1].x, acc[2*k+1].y);
        __syncthreads();
    }

    // Epilogue: group k = tid>>7; sum 8 neurons at stride 128 (conflict-free),
    // fp32 accumulation; 64-lane butterfly; wave wv covers half of group wv>>1.
    {
        const int k    = tid >> 7;
        const int base = k * 1024 + (tid & 127);
        float4 v = make_float4(0.f, 0.f, 0.f, 0.f);
#pragma unroll
        for (int i = 0; i < 8; ++i) {
            float4 t = unpack4(h[base + 128 * i]);
            v.x += t.x; v.y += t.y; v.z += t.z; v.w += t.w;
        }
#pragma unroll
        for (int off = 32; off > 0; off >>= 1) {
            v.x += __shfl_down(v.x, off);
            v.y += __shfl_down(v.y, off);
            v.z += __shfl_down(v.z, off);
            v.w += __shfl_down(v.w, off);
        }
        if ((tid & 63) == 0) warr[tid >> 6] = v;
    }
    __syncthreads();
    if (tid < OUT_DIM) {
        float4 a = warr[2 * tid], b = warr[2 * tid + 1];
        vals[0][tid] = (a.x + b.x) * INV_TAU;
        vals[1][tid] = (a.y + b.y) * INV_TAU;
        vals[2][tid] = (a.z + b.z) * INV_TAU;
        vals[3][tid] = (a.w + b.w) * INV_TAU;
    }
    __syncthreads();
    if (tid < TB * OUT_DIM) {
        int t  = tid >> 3;
        int oo = tid & 7;
        float q = scaler_b[oo];
#pragma unroll
        for (int o2 = 0; o2 < OUT_DIM; ++o2)
            q = fmaf(vals[t][o2], scaler_w[oo * OUT_DIM + o2], q);
        out[(size_t)(b0 + t) * OUT_DIM + oo] = q;
    }
}

extern "C" void kernel_launch(void* const* d_in, const int* in_sizes, int n_in,
                              void* d_out, int out_size, void* d_ws, size_t ws_size,
                              hipStream_t stream)
{
    const float* x        = (const float*)d_in[0];
    const float* logic_w  = (const float*)d_in[1];
    const float* scaler_w = (const float*)d_in[2];
    const float* scaler_b = (const float*)d_in[3];
    const int*   idx0_a   = (const int*)d_in[4];
    const int*   idx0_b   = (const int*)d_in[5];
    const int*   idx_a    = (const int*)d_in[6];
    const int*   idx_b    = (const int*)d_in[7];
    float* out = (float*)d_out;

    const int n = N_LAYERS * HIDDEN;                 // 49152
    uint2*        coefp = (uint2*)d_ws;              // 384 KB
    unsigned int* idxp  = (unsigned int*)((char*)d_ws + (size_t)n * sizeof(uint2)); // 192 KB

    prep_kernel<<<(n + 255) / 256, 256, 0, stream>>>(logic_w, idx0_a, idx0_b,
                                                     idx_a, idx_b, coefp, idxp, n);
    net_kernel<<<BATCH / TB, NTH, 0, stream>>>(x, coefp, idxp,
                                               scaler_w, scaler_b, out);
}

// Round 5
// 128.944 us; speedup vs baseline: 1.0157x; 1.0157x over previous
//
#include <hip/hip_runtime.h>
#include <hip/hip_fp16.h>

// Problem constants (from reference)
constexpr int BATCH    = 4096;
constexpr int IN_DIM   = 1024;
constexpr int HIDDEN   = 8192;
constexpr int N_LAYERS = 6;
constexpr int OUT_DIM  = 8;
constexpr float INV_TAU = 0.1f;

// Tiling
constexpr int TB   = 4;             // batch rows per workgroup
constexpr int NTH  = 1024;          // threads per block (16 waves)
constexpr int NPT  = HIDDEN / NTH;  // neurons per thread = 8 (strided by 1024)
constexpr int NWAVES = NTH / 64;    // 16

__device__ __forceinline__ __half2 u2h(unsigned int u) {
    union { unsigned int u; __half2 h; } v; v.u = u; return v.h;
}
__device__ __forceinline__ unsigned int h2u(__half2 h) {
    union { unsigned int u; __half2 h; } v; v.h = h; return v.u;
}

// pack 4 fp32 -> 4 fp16 in a uint2
__device__ __forceinline__ uint2 pack4(float4 v) {
    __half2 lo = __float22half2_rn(make_float2(v.x, v.y));
    __half2 hi = __float22half2_rn(make_float2(v.z, v.w));
    uint2 r; r.x = h2u(lo); r.y = h2u(hi); return r;
}
__device__ __forceinline__ float4 unpack4(uint2 p) {
    float2 a = __half22float2(u2h(p.x));
    float2 b = __half22float2(u2h(p.y));
    return make_float4(a.x, a.y, b.x, b.y);
}

// ---------------------------------------------------------------------------
// Kernel 1: packed per-neuron records:
//   coefp[l*H+j] = 4 fp16 gate coefs (c0,c1 | c2,c3)
//   idxp [l*H+j] = ia | (ib << 16)
// ---------------------------------------------------------------------------
__global__ void prep_kernel(const float* __restrict__ logic_w,
                            const int* __restrict__ idx0_a,
                            const int* __restrict__ idx0_b,
                            const int* __restrict__ idx_a,
                            const int* __restrict__ idx_b,
                            uint2* __restrict__ coefp,
                            unsigned int* __restrict__ idxp, int n)
{
    int id = blockIdx.x * blockDim.x + threadIdx.x;
    if (id >= n) return;
    const int l = id / HIDDEN;
    const int j = id - l * HIDDEN;

    int ia, ib;
    if (l == 0) { ia = idx0_a[j]; ib = idx0_b[j]; }
    else        { ia = idx_a[(size_t)(l - 1) * HIDDEN + j];
                  ib = idx_b[(size_t)(l - 1) * HIDDEN + j]; }
    idxp[id] = (unsigned int)ia | ((unsigned int)ib << 16);

    const float4* w4 = (const float4*)(logic_w + (size_t)id * 16);
    float4 wa = w4[0], wb = w4[1], wc = w4[2], wd = w4[3];
    float wv[16] = {wa.x, wa.y, wa.z, wa.w, wb.x, wb.y, wb.z, wb.w,
                    wc.x, wc.y, wc.z, wc.w, wd.x, wd.y, wd.z, wd.w};
    float m = wv[0];
#pragma unroll
    for (int i = 1; i < 16; ++i) m = fmaxf(m, wv[i]);
    float e[16];
    float s = 0.f;
#pragma unroll
    for (int i = 0; i < 16; ++i) { e[i] = expf(wv[i] - m); s += e[i]; }
    float inv = 1.f / s;
    const float G0[16] = {0,0,0,0,0,0,0,0, 1,1,1,1,1,1,1,1};
    const float G1[16] = {0,0,1,1,0,0,1,1, -1,-1,0,0,-1,-1,0,0};
    const float G2[16] = {0,0,0,0,1,1,1,1, -1,-1,-1,-1,0,0,0,0};
    const float G3[16] = {0,1,-1,0,-1,0,-2,-1, 1,2,0,1,0,1,-1,0};
    float c0 = 0.f, c1 = 0.f, c2 = 0.f, c3 = 0.f;
#pragma unroll
    for (int i = 0; i < 16; ++i) {
        float p = e[i] * inv;
        c0 = fmaf(p, G0[i], c0);
        c1 = fmaf(p, G1[i], c1);
        c2 = fmaf(p, G2[i], c2);
        c3 = fmaf(p, G3[i], c3);
    }
    coefp[id] = pack4(make_float4(c0, c1, c2, c3));
}

// gate in packed fp16: r = (c0 + c1*a) + b*(c2 + c3*a), both half2 halves.
// c.x = (c0|c1), c.y = (c2|c3); splats fold into v_pk op_sel.
__device__ __forceinline__ uint2 gateh(uint2 a, uint2 b, uint2 c) {
    __half2 cp01 = u2h(c.x), cp23 = u2h(c.y);
    __half2 c0 = __low2half2(cp01), c1 = __high2half2(cp01);
    __half2 c2 = __low2half2(cp23), c3 = __high2half2(cp23);
    __half2 alo = u2h(a.x), ahi = u2h(a.y);
    __half2 blo = u2h(b.x), bhi = u2h(b.y);
    __half2 rlo = __hfma2(blo, __hfma2(c3, alo, c2), __hfma2(c1, alo, c0));
    __half2 rhi = __hfma2(bhi, __hfma2(c3, ahi, c2), __hfma2(c1, ahi, c0));
    uint2 r; r.x = h2u(rlo); r.y = h2u(rhi); return r;
}

// ---------------------------------------------------------------------------
// Kernel 2: fused network. TB=4 rows/block, h = fp16x4 (uint2)[HIDDEN] = 64 KB
// -> 2 blocks/CU. STRIDED ownership j = k*1024 + tid: LDS writes have 8 B
// lane stride -> all 32 banks covered -> conflict-free (R4's consecutive
// ownership gave 64 B lane stride -> 2 banks -> conflicts doubled).
// Gate math entirely in v_pk_fma_f16 (validated in R4: VALUBusy 59->22%).
// ---------------------------------------------------------------------------
__global__ __launch_bounds__(NTH) void net_kernel(
    const float*  __restrict__ x,
    const uint2*  __restrict__ coefp,
    const unsigned int* __restrict__ idxp,
    const float*  __restrict__ scaler_w, const float* __restrict__ scaler_b,
    float* __restrict__ out)
{
    __shared__ uint2 h[HIDDEN];             // 64 KB
    __shared__ uint2 hx[IN_DIM];            // 8 KB
    __shared__ float4 warr[NWAVES];         // 256 B
    __shared__ float  vals[TB][OUT_DIM];    // 128 B

    const int tid = threadIdx.x;
    const int b0  = blockIdx.x * TB;

    // Load + binarize input tile (NTH == IN_DIM)
    {
        float4 xv;
        xv.x = (x[(size_t)(b0 + 0) * IN_DIM + tid] > 0.5f) ? 1.f : 0.f;
        xv.y = (x[(size_t)(b0 + 1) * IN_DIM + tid] > 0.5f) ? 1.f : 0.f;
        xv.z = (x[(size_t)(b0 + 2) * IN_DIM + tid] > 0.5f) ? 1.f : 0.f;
        xv.w = (x[(size_t)(b0 + 3) * IN_DIM + tid] > 0.5f) ? 1.f : 0.f;
        hx[tid] = pack4(xv);
    }
    __syncthreads();

    uint2 acc[NPT];                          // fp16-packed results (16 VGPRs)

    // Layer 0: gather from hx
#pragma unroll
    for (int k = 0; k < NPT; ++k) {
        int j = k * NTH + tid;
        unsigned int pr = idxp[j];
        acc[k] = gateh(hx[pr & 0xffffu], hx[pr >> 16], coefp[j]);
    }
#pragma unroll
    for (int k = 0; k < NPT; ++k) h[k * NTH + tid] = acc[k];
    __syncthreads();

    // Layers 1..5: in-place on h (reads land in regs before writes)
    for (int l = 1; l < N_LAYERS; ++l) {
        const unsigned int* ip = idxp  + (size_t)l * HIDDEN;
        const uint2*        cp = coefp + (size_t)l * HIDDEN;
#pragma unroll
        for (int k = 0; k < NPT; ++k) {
            int j = k * NTH + tid;
            unsigned int pr = ip[j];
            acc[k] = gateh(h[pr & 0xffffu], h[pr >> 16], cp[j]);
        }
        __syncthreads();                    // all reads of h done
#pragma unroll
        for (int k = 0; k < NPT; ++k) h[k * NTH + tid] = acc[k];
        __syncthreads();
    }

    // Epilogue: group k = tid>>7; sum 8 neurons at stride 128 (conflict-free),
    // fp32 accumulation; 64-lane butterfly; wave wv covers half of group wv>>1.
    {
        const int k    = tid >> 7;
        const int base = k * 1024 + (tid & 127);
        float4 v = make_float4(0.f, 0.f, 0.f, 0.f);
#pragma unroll
        for (int i = 0; i < 8; ++i) {
            float4 t = unpack4(h[base + 128 * i]);
            v.x += t.x; v.y += t.y; v.z += t.z; v.w += t.w;
        }
#pragma unroll
        for (int off = 32; off > 0; off >>= 1) {
            v.x += __shfl_down(v.x, off);
            v.y += __shfl_down(v.y, off);
            v.z += __shfl_down(v.z, off);
            v.w += __shfl_down(v.w, off);
        }
        if ((tid & 63) == 0) warr[tid >> 6] = v;
    }
    __syncthreads();
    if (tid < OUT_DIM) {
        float4 a = warr[2 * tid], b = warr[2 * tid + 1];
        vals[0][tid] = (a.x + b.x) * INV_TAU;
        vals[1][tid] = (a.y + b.y) * INV_TAU;
        vals[2][tid] = (a.z + b.z) * INV_TAU;
        vals[3][tid] = (a.w + b.w) * INV_TAU;
    }
    __syncthreads();
    if (tid < TB * OUT_DIM) {
        int t  = tid >> 3;
        int oo = tid & 7;
        float q = scaler_b[oo];
#pragma unroll
        for (int o2 = 0; o2 < OUT_DIM; ++o2)
            q = fmaf(vals[t][o2], scaler_w[oo * OUT_DIM + o2], q);
        out[(size_t)(b0 + t) * OUT_DIM + oo] = q;
    }
}

extern "C" void kernel_launch(void* const* d_in, const int* in_sizes, int n_in,
                              void* d_out, int out_size, void* d_ws, size_t ws_size,
                              hipStream_t stream)
{
    const float* x        = (const float*)d_in[0];
    const float* logic_w  = (const float*)d_in[1];
    const float* scaler_w = (const float*)d_in[2];
    const float* scaler_b = (const float*)d_in[3];
    const int*   idx0_a   = (const int*)d_in[4];
    const int*   idx0_b   = (const int*)d_in[5];
    const int*   idx_a    = (const int*)d_in[6];
    const int*   idx_b    = (const int*)d_in[7];
    float* out = (float*)d_out;

    const int n = N_LAYERS * HIDDEN;                 // 49152
    uint2*        coefp = (uint2*)d_ws;              // 384 KB
    unsigned int* idxp  = (unsigned int*)((char*)d_ws + (size_t)n * sizeof(uint2)); // 192 KB

    prep_kernel<<<(n + 255) / 256, 256, 0, stream>>>(logic_w, idx0_a, idx0_b,
                                                     idx_a, idx_b, coefp, idxp, n);
    net_kernel<<<BATCH / TB, NTH, 0, stream>>>(x, coefp, idxp,
                                               scaler_w, scaler_b, out);
}